// Round 1
// baseline (947.560 us; speedup 1.0000x reference)
//
#include <hip/hip_runtime.h>

#define NN 50000
#define NE 800000
#define H64 64

// ---------------- degree ----------------
__global__ void k_init_deg(float* __restrict__ deg) {
    int i = blockIdx.x * 256 + threadIdx.x;
    if (i < NN) deg[i] = 1.0f;  // self-loop
}

__global__ void k_deg_scatter(const int* __restrict__ dst, float* __restrict__ deg) {
    int e = blockIdx.x * 256 + threadIdx.x;
    if (e < NE) atomicAdd(&deg[dst[e]], 1.0f);
}

__global__ void k_rsqrt(float* __restrict__ deg) {
    int i = blockIdx.x * 256 + threadIdx.x;
    if (i < NN) deg[i] = rsqrtf(deg[i]);  // deg >= 1 always (self-loop)
}

// ---------------- fc stack: X = relu(nf@W1+b1)@W2+b2 ----------------
__global__ __launch_bounds__(256) void k_fc(
    const float* __restrict__ nf,
    const float* __restrict__ W1, const float* __restrict__ b1,
    const float* __restrict__ W2, const float* __restrict__ b2,
    float* __restrict__ X) {
    __shared__ float sW1[128 * 32];
    __shared__ float sW2[32 * 64];
    __shared__ float sb1[32];
    __shared__ float sb2[64];
    __shared__ float sx[4 * 128];
    __shared__ float sh[4 * 32];
    int t = threadIdx.x;
    for (int i = t; i < 128 * 32; i += 256) sW1[i] = W1[i];
    for (int i = t; i < 32 * 64; i += 256) sW2[i] = W2[i];
    if (t < 32) sb1[t] = b1[t];
    if (t < 64) sb2[t] = b2[t];
    __syncthreads();
    const int ngroups = NN / 4;  // 12500
    for (int g = blockIdx.x; g < ngroups; g += gridDim.x) {
        int base = g * 4;
        sx[t]       = nf[base * 128 + t];
        sx[t + 256] = nf[base * 128 + 256 + t];
        __syncthreads();
        if (t < 128) {
            int nl = t >> 5, j = t & 31;
            float s = sb1[j];
            #pragma unroll
            for (int k = 0; k < 128; ++k) s += sx[nl * 128 + k] * sW1[k * 32 + j];
            sh[nl * 32 + j] = fmaxf(s, 0.0f);
        }
        __syncthreads();
        {
            int nl = t >> 6, c = t & 63;
            float s = sb2[c];
            #pragma unroll
            for (int j = 0; j < 32; ++j) s += sh[nl * 32 + j] * sW2[j * 64 + c];
            X[(base + nl) * H64 + c] = s;
        }
        __syncthreads();
    }
}

// ---------------- conv GEMM: H[n] = disq[n] * (X[n] @ W) ----------------
__global__ __launch_bounds__(256) void k_gemm64(
    const float* __restrict__ X, const float* __restrict__ W,
    const float* __restrict__ disq, float* __restrict__ Hout) {
    __shared__ float sW[64 * 64];
    __shared__ float sx[4 * 64];
    int t = threadIdx.x;
    for (int i = t; i < 64 * 64; i += 256) sW[i] = W[i];
    __syncthreads();
    const int ngroups = NN / 4;  // 12500
    for (int g = blockIdx.x; g < ngroups; g += gridDim.x) {
        int base = g * 4;
        sx[t] = X[base * 64 + t];
        __syncthreads();
        int nl = t >> 6, c = t & 63;
        float s = 0.0f;
        #pragma unroll
        for (int k = 0; k < 64; ++k) s += sx[nl * 64 + k] * sW[k * 64 + c];
        Hout[(base + nl) * 64 + c] = disq[base + nl] * s;
        __syncthreads();
    }
}

// ---------------- edge scatter: A[dst] += H[src], wave-per-edge ----------------
__global__ __launch_bounds__(256) void k_scatter(
    const float* __restrict__ Hin, const int* __restrict__ src,
    const int* __restrict__ dst, float* __restrict__ A) {
    int gid = blockIdx.x * 256 + threadIdx.x;
    int e = gid >> 6;
    int c = gid & 63;
    if (e < NE) {
        int s = src[e], d = dst[e];
        atomicAdd(&A[d * 64 + c], Hin[s * 64 + c]);
    }
}

// ---------------- finalize: out = act(disq*(A+H)+b) [+res] ----------------
__global__ __launch_bounds__(256) void k_finalize(
    const float* __restrict__ A, const float* __restrict__ Hin,
    const float* __restrict__ disq, const float* __restrict__ b,
    const float* __restrict__ res, float* __restrict__ out, int do_lrelu) {
    int idx = blockIdx.x * 256 + threadIdx.x;
    if (idx < NN * 64) {
        int n = idx >> 6, c = idx & 63;
        float v = disq[n] * (A[idx] + Hin[idx]) + b[c];
        if (do_lrelu) v = (v >= 0.0f) ? v : 0.2f * v;
        if (res) v += res[idx];
        out[idx] = v;
    }
}

// ---------------- final projection 64 -> 2, wave-per-node ----------------
__global__ __launch_bounds__(256) void k_final(
    const float* __restrict__ X, const float* __restrict__ FW,
    const float* __restrict__ fb, float* __restrict__ out) {
    int wave = threadIdx.x >> 6, lane = threadIdx.x & 63;
    int node = blockIdx.x * 4 + wave;
    if (node >= NN) return;
    float x = X[node * 64 + lane];
    float p0 = x * FW[lane * 2 + 0];
    float p1 = x * FW[lane * 2 + 1];
    for (int off = 32; off; off >>= 1) {
        p0 += __shfl_xor(p0, off, 64);
        p1 += __shfl_xor(p1, off, 64);
    }
    if (lane == 0) {
        out[node * 2 + 0] = p0 + fb[0];
        out[node * 2 + 1] = p1 + fb[1];
    }
}

extern "C" void kernel_launch(void* const* d_in, const int* in_sizes, int n_in,
                              void* d_out, int out_size, void* d_ws, size_t ws_size,
                              hipStream_t stream) {
    const float* nf   = (const float*)d_in[0];
    const int*   ei   = (const int*)d_in[1];
    const float* fc1W = (const float*)d_in[2];
    const float* fc1b = (const float*)d_in[3];
    const float* fc2W = (const float*)d_in[4];
    const float* fc2b = (const float*)d_in[5];
    const float* cW[4] = {(const float*)d_in[6], (const float*)d_in[8],
                          (const float*)d_in[10], (const float*)d_in[12]};
    const float* cb[4] = {(const float*)d_in[7], (const float*)d_in[9],
                          (const float*)d_in[11], (const float*)d_in[13]};
    const float* fW = (const float*)d_in[14];
    const float* fb = (const float*)d_in[15];
    const int* src = ei;
    const int* dst = ei + NE;

    float* ws   = (float*)d_ws;
    float* disq = ws;                     // NN (padded to 50048)
    float* B0   = ws + 50048;             // NN*64
    float* B1   = B0 + (size_t)NN * 64;   // NN*64
    float* Hh   = B1 + (size_t)NN * 64;   // NN*64
    float* Aa   = Hh + (size_t)NN * 64;   // NN*64

    // degree + rsqrt
    k_init_deg<<<(NN + 255) / 256, 256, 0, stream>>>(disq);
    k_deg_scatter<<<(NE + 255) / 256, 256, 0, stream>>>(dst, disq);
    k_rsqrt<<<(NN + 255) / 256, 256, 0, stream>>>(disq);

    // fc stack -> B0
    k_fc<<<2048, 256, 0, stream>>>(nf, fc1W, fc1b, fc2W, fc2b, B0);

    auto conv = [&](const float* Xin, const float* W, const float* b,
                    const float* res, float* Xout, int lrelu) {
        k_gemm64<<<2048, 256, 0, stream>>>(Xin, W, disq, Hh);
        hipMemsetAsync(Aa, 0, (size_t)NN * 64 * sizeof(float), stream);
        k_scatter<<<(NE * 64) / 256, 256, 0, stream>>>(Hh, src, dst, Aa);
        k_finalize<<<(NN * 64) / 256, 256, 0, stream>>>(Aa, Hh, disq, b, res, Xout, lrelu);
    };

    conv(B0, cW[0], cb[0], nullptr, B1, 1);  // out1 = B1
    conv(B1, cW[1], cb[1], B1, B0, 1);       // out2 = lrelu(.)+out1 -> B0
    conv(B0, cW[2], cb[2], nullptr, B1, 1);  // out3 -> B1
    conv(B1, cW[3], cb[3], B0, Aa, 0);       // out4 = . + out2 -> Aa (in-place over A)

    k_final<<<NN / 4, 256, 0, stream>>>(Aa, fW, fb, (float*)d_out);
}

// Round 2
// 489.457 us; speedup vs baseline: 1.9359x; 1.9359x over previous
//
#include <hip/hip_runtime.h>

#define NN 50000
#define NE 800000

// ---------------- CSR build ----------------
__global__ void k_hist(const int* __restrict__ dst, int* __restrict__ cnt) {
    int e = blockIdx.x * 256 + threadIdx.x;
    if (e < NE) atomicAdd(&cnt[dst[e]], 1);
}

__global__ void k_disq(const int* __restrict__ cnt, float* __restrict__ disq) {
    int i = blockIdx.x * 256 + threadIdx.x;
    if (i < NN) disq[i] = rsqrtf((float)cnt[i] + 1.0f);  // +1 self-loop
}

// single-block inclusive scan: rowptr[i+1] = sum(cnt[0..i]), rowptr[0] = 0
__global__ __launch_bounds__(1024) void k_scan(const int* __restrict__ cnt,
                                               int* __restrict__ rowptr) {
    __shared__ int wsum[16];
    __shared__ int carry;
    int t = threadIdx.x, wave = t >> 6, lane = t & 63;
    if (t == 0) { carry = 0; rowptr[0] = 0; }
    __syncthreads();
    for (int base = 0; base < NN; base += 1024) {
        int i = base + t;
        int x = (i < NN) ? cnt[i] : 0;
        for (int off = 1; off < 64; off <<= 1) {
            int y = __shfl_up(x, off, 64);
            if (lane >= off) x += y;
        }
        if (lane == 63) wsum[wave] = x;
        __syncthreads();
        if (wave == 0 && lane < 16) {
            int w = wsum[lane];
            for (int off = 1; off < 16; off <<= 1) {
                int y = __shfl_up(w, off, 16);
                if (lane >= off) w += y;
            }
            wsum[lane] = w;
        }
        __syncthreads();
        int incl = carry + ((wave > 0) ? wsum[wave - 1] : 0) + x;
        if (i < NN) rowptr[i + 1] = incl;
        __syncthreads();
        if (t == 1023) carry = incl;
        __syncthreads();
    }
}

__global__ void k_fill(const int* __restrict__ src, const int* __restrict__ dst,
                       const int* __restrict__ rowptr, int* __restrict__ cur,
                       int* __restrict__ esrc) {
    int e = blockIdx.x * 256 + threadIdx.x;
    if (e < NE) {
        int d = dst[e];
        int pos = rowptr[d] + atomicAdd(&cur[d], 1);
        esrc[pos] = src[e];
    }
}

// ---------------- fc stack: X = relu(nf@W1+b1)@W2+b2 ----------------
__global__ __launch_bounds__(256) void k_fc(
    const float* __restrict__ nf,
    const float* __restrict__ W1, const float* __restrict__ b1,
    const float* __restrict__ W2, const float* __restrict__ b2,
    float* __restrict__ X) {
    __shared__ float sW1[128 * 32];
    __shared__ float sW2[32 * 64];
    __shared__ float sb1[32];
    __shared__ float sb2[64];
    __shared__ float sx[4 * 128];
    __shared__ float sh[4 * 32];
    int t = threadIdx.x;
    for (int i = t; i < 128 * 32; i += 256) sW1[i] = W1[i];
    for (int i = t; i < 32 * 64; i += 256) sW2[i] = W2[i];
    if (t < 32) sb1[t] = b1[t];
    if (t < 64) sb2[t] = b2[t];
    __syncthreads();
    const int ngroups = NN / 4;  // 12500
    for (int g = blockIdx.x; g < ngroups; g += gridDim.x) {
        int base = g * 4;
        sx[t]       = nf[base * 128 + t];
        sx[t + 256] = nf[base * 128 + 256 + t];
        __syncthreads();
        if (t < 128) {
            int nl = t >> 5, j = t & 31;
            float s = sb1[j];
            #pragma unroll
            for (int k = 0; k < 128; ++k) s += sx[nl * 128 + k] * sW1[k * 32 + j];
            sh[nl * 32 + j] = fmaxf(s, 0.0f);
        }
        __syncthreads();
        {
            int nl = t >> 6, c = t & 63;
            float s = sb2[c];
            #pragma unroll
            for (int j = 0; j < 32; ++j) s += sh[nl * 32 + j] * sW2[j * 64 + c];
            X[(base + nl) * 64 + c] = s;
        }
        __syncthreads();
    }
}

// ---------------- conv GEMM: H[n] = disq[n] * (X[n] @ W) ----------------
__global__ __launch_bounds__(256) void k_gemm64(
    const float* __restrict__ X, const float* __restrict__ W,
    const float* __restrict__ disq, float* __restrict__ Hout) {
    __shared__ float sW[64 * 64];
    __shared__ float sx[4 * 64];
    int t = threadIdx.x;
    for (int i = t; i < 64 * 64; i += 256) sW[i] = W[i];
    __syncthreads();
    const int ngroups = NN / 4;  // 12500
    for (int g = blockIdx.x; g < ngroups; g += gridDim.x) {
        int base = g * 4;
        sx[t] = X[base * 64 + t];
        __syncthreads();
        int nl = t >> 6, c = t & 63;
        float s = 0.0f;
        #pragma unroll
        for (int k = 0; k < 64; ++k) s += sx[nl * 64 + k] * sW[k * 64 + c];
        Hout[(base + nl) * 64 + c] = disq[base + nl] * s;
        __syncthreads();
    }
}

// ---------------- CSR conv: out = act(disq*(sum_neigh H + H_self) + b) [+res]
// one wave per node, lane = channel
__global__ __launch_bounds__(256) void k_csr_conv(
    const float* __restrict__ H, const int* __restrict__ rowptr,
    const int* __restrict__ esrc, const float* __restrict__ disq,
    const float* __restrict__ b, const float* __restrict__ res,
    float* __restrict__ out, int do_lrelu) {
    int wave = threadIdx.x >> 6, lane = threadIdx.x & 63;
    int n = blockIdx.x * 4 + wave;
    if (n >= NN) return;
    int beg = rowptr[n], end = rowptr[n + 1];
    float acc = H[(size_t)n * 64 + lane];  // self-loop
    int i = beg;
    for (; i + 1 < end; i += 2) {
        int s0 = esrc[i], s1 = esrc[i + 1];
        float h0 = H[(size_t)s0 * 64 + lane];
        float h1 = H[(size_t)s1 * 64 + lane];
        acc += h0 + h1;
    }
    if (i < end) acc += H[(size_t)esrc[i] * 64 + lane];
    float v = disq[n] * acc + b[lane];
    if (do_lrelu) v = (v >= 0.0f) ? v : 0.2f * v;
    if (res) v += res[(size_t)n * 64 + lane];
    out[(size_t)n * 64 + lane] = v;
}

// ---------------- CSR conv fused with final 64->2 projection (conv4) ----
__global__ __launch_bounds__(256) void k_csr_conv_final(
    const float* __restrict__ H, const int* __restrict__ rowptr,
    const int* __restrict__ esrc, const float* __restrict__ disq,
    const float* __restrict__ b, const float* __restrict__ res,
    const float* __restrict__ FW, const float* __restrict__ fb,
    float* __restrict__ out) {
    int wave = threadIdx.x >> 6, lane = threadIdx.x & 63;
    int n = blockIdx.x * 4 + wave;
    if (n >= NN) return;
    int beg = rowptr[n], end = rowptr[n + 1];
    float acc = H[(size_t)n * 64 + lane];
    int i = beg;
    for (; i + 1 < end; i += 2) {
        int s0 = esrc[i], s1 = esrc[i + 1];
        float h0 = H[(size_t)s0 * 64 + lane];
        float h1 = H[(size_t)s1 * 64 + lane];
        acc += h0 + h1;
    }
    if (i < end) acc += H[(size_t)esrc[i] * 64 + lane];
    float v = disq[n] * acc + b[lane] + res[(size_t)n * 64 + lane];  // out4
    float p0 = v * FW[lane * 2 + 0];
    float p1 = v * FW[lane * 2 + 1];
    for (int off = 32; off; off >>= 1) {
        p0 += __shfl_xor(p0, off, 64);
        p1 += __shfl_xor(p1, off, 64);
    }
    if (lane == 0) {
        out[n * 2 + 0] = p0 + fb[0];
        out[n * 2 + 1] = p1 + fb[1];
    }
}

extern "C" void kernel_launch(void* const* d_in, const int* in_sizes, int n_in,
                              void* d_out, int out_size, void* d_ws, size_t ws_size,
                              hipStream_t stream) {
    const float* nf   = (const float*)d_in[0];
    const int*   ei   = (const int*)d_in[1];
    const float* fc1W = (const float*)d_in[2];
    const float* fc1b = (const float*)d_in[3];
    const float* fc2W = (const float*)d_in[4];
    const float* fc2b = (const float*)d_in[5];
    const float* cW[4] = {(const float*)d_in[6], (const float*)d_in[8],
                          (const float*)d_in[10], (const float*)d_in[12]};
    const float* cb[4] = {(const float*)d_in[7], (const float*)d_in[9],
                          (const float*)d_in[11], (const float*)d_in[13]};
    const float* fW = (const float*)d_in[14];
    const float* fb = (const float*)d_in[15];
    const int* src = ei;
    const int* dst = ei + NE;

    float* ws     = (float*)d_ws;
    float* disq   = ws;                          // 50048 f
    int*   cnt    = (int*)(ws + 50048);          // 50048 i (histogram, then cursor)
    int*   rowptr = cnt + 50048;                 // 50056 i
    int*   esrc   = rowptr + 50056;              // 800000 i
    float* B0     = (float*)(esrc + 800000);     // NN*64 f
    float* B1     = B0 + (size_t)NN * 64;        // NN*64 f
    float* Hh     = B1 + (size_t)NN * 64;        // NN*64 f

    // ---- CSR build (once, shared by all 4 convs) ----
    hipMemsetAsync(cnt, 0, 50048 * sizeof(int), stream);
    k_hist<<<(NE + 255) / 256, 256, 0, stream>>>(dst, cnt);
    k_disq<<<(NN + 255) / 256, 256, 0, stream>>>(cnt, disq);
    k_scan<<<1, 1024, 0, stream>>>(cnt, rowptr);
    hipMemsetAsync(cnt, 0, 50048 * sizeof(int), stream);
    k_fill<<<(NE + 255) / 256, 256, 0, stream>>>(src, dst, rowptr, cnt, esrc);

    // ---- fc stack -> B0 ----
    k_fc<<<2048, 256, 0, stream>>>(nf, fc1W, fc1b, fc2W, fc2b, B0);

    const int cgrid = (NN + 3) / 4;

    // conv1: out1 -> B1
    k_gemm64<<<2048, 256, 0, stream>>>(B0, cW[0], disq, Hh);
    k_csr_conv<<<cgrid, 256, 0, stream>>>(Hh, rowptr, esrc, disq, cb[0], nullptr, B1, 1);
    // conv2: out2 = lrelu(conv)+out1 -> B0
    k_gemm64<<<2048, 256, 0, stream>>>(B1, cW[1], disq, Hh);
    k_csr_conv<<<cgrid, 256, 0, stream>>>(Hh, rowptr, esrc, disq, cb[1], B1, B0, 1);
    // conv3: out3 -> B1
    k_gemm64<<<2048, 256, 0, stream>>>(B0, cW[2], disq, Hh);
    k_csr_conv<<<cgrid, 256, 0, stream>>>(Hh, rowptr, esrc, disq, cb[2], nullptr, B1, 1);
    // conv4 + final projection -> d_out
    k_gemm64<<<2048, 256, 0, stream>>>(B1, cW[3], disq, Hh);
    k_csr_conv_final<<<cgrid, 256, 0, stream>>>(Hh, rowptr, esrc, disq, cb[3], B0,
                                                fW, fb, (float*)d_out);
}

// Round 3
// 414.148 us; speedup vs baseline: 2.2880x; 1.1818x over previous
//
#include <hip/hip_runtime.h>

#define NN 50000
#define NE 800000

__device__ inline float rlf(float v, int l) {
    return __int_as_float(__builtin_amdgcn_readlane(__float_as_int(v), l));
}

// ---------------- CSR build ----------------
__global__ void k_hist(const int* __restrict__ dst, int* __restrict__ cnt) {
    int e = blockIdx.x * 256 + threadIdx.x;
    if (e < NE) atomicAdd(&cnt[dst[e]], 1);
}

__global__ void k_disq(const int* __restrict__ cnt, float* __restrict__ disq) {
    int i = blockIdx.x * 256 + threadIdx.x;
    if (i < NN) disq[i] = rsqrtf((float)cnt[i] + 1.0f);  // +1 self-loop
}

// single-block inclusive scan: rowptr[i+1] = sum(cnt[0..i]), rowptr[0] = 0
__global__ __launch_bounds__(1024) void k_scan(const int* __restrict__ cnt,
                                               int* __restrict__ rowptr) {
    __shared__ int wsum[16];
    __shared__ int carry;
    int t = threadIdx.x, wave = t >> 6, lane = t & 63;
    if (t == 0) { carry = 0; rowptr[0] = 0; }
    __syncthreads();
    for (int base = 0; base < NN; base += 1024) {
        int i = base + t;
        int x = (i < NN) ? cnt[i] : 0;
        for (int off = 1; off < 64; off <<= 1) {
            int y = __shfl_up(x, off, 64);
            if (lane >= off) x += y;
        }
        if (lane == 63) wsum[wave] = x;
        __syncthreads();
        if (wave == 0 && lane < 16) {
            int w = wsum[lane];
            for (int off = 1; off < 16; off <<= 1) {
                int y = __shfl_up(w, off, 16);
                if (lane >= off) w += y;
            }
            wsum[lane] = w;
        }
        __syncthreads();
        int incl = carry + ((wave > 0) ? wsum[wave - 1] : 0) + x;
        if (i < NN) rowptr[i + 1] = incl;
        __syncthreads();
        if (t == 1023) carry = incl;
        __syncthreads();
    }
}

__global__ void k_fill(const int* __restrict__ src, const int* __restrict__ dst,
                       const int* __restrict__ rowptr, int* __restrict__ cur,
                       int* __restrict__ esrc) {
    int e = blockIdx.x * 256 + threadIdx.x;
    if (e < NE) {
        int d = dst[e];
        int pos = rowptr[d] + atomicAdd(&cur[d], 1);
        esrc[pos] = src[e];
    }
}

// ---------------- fc stack: X = relu(nf@W1+b1)@W2+b2 ----------------
// wave per node; W1/W2 columns register-resident; x broadcast via readlane
__global__ __launch_bounds__(256) void k_fc(
    const float* __restrict__ nf,
    const float* __restrict__ W1, const float* __restrict__ b1,
    const float* __restrict__ W2, const float* __restrict__ b2,
    float* __restrict__ X) {
    int lane = threadIdx.x & 63;
    int c = lane & 31, h = lane >> 5;
    int wid = (blockIdx.x * 256 + threadIdx.x) >> 6;
    int nwaves = (gridDim.x * 256) >> 6;
    float w1[64], w2[32];
    #pragma unroll
    for (int j = 0; j < 64; ++j) w1[j] = W1[(h * 64 + j) * 32 + c];
    #pragma unroll
    for (int j = 0; j < 32; ++j) w2[j] = W2[j * 64 + lane];
    float b1c = b1[c], b2l = b2[lane];
    for (int n = wid; n < NN; n += nwaves) {
        float x0 = nf[(size_t)n * 128 + lane];
        float x1 = nf[(size_t)n * 128 + 64 + lane];
        float s = 0.f;
        #pragma unroll
        for (int j = 0; j < 64; ++j) {
            float xa = rlf(x0, j), xb = rlf(x1, j);
            s = fmaf(h ? xb : xa, w1[j], s);
        }
        s += __shfl_xor(s, 32, 64);           // combine k-halves
        float hv = fmaxf(s + b1c, 0.f);       // lane l holds h1[l&31]
        float o = b2l;
        #pragma unroll
        for (int j = 0; j < 32; ++j) o = fmaf(rlf(hv, j), w2[j], o);
        X[(size_t)n * 64 + lane] = o;
    }
}

// ---------------- conv GEMM: H[n] = disq[n] * (X[n] @ W) ----------------
// wave per node, lane = output channel, W column in 64 VGPRs, no LDS
__global__ __launch_bounds__(256) void k_gemm64(
    const float* __restrict__ X, const float* __restrict__ W,
    const float* __restrict__ disq, float* __restrict__ Hout) {
    int lane = threadIdx.x & 63;
    int wid = (blockIdx.x * 256 + threadIdx.x) >> 6;
    int nwaves = (gridDim.x * 256) >> 6;
    float wcol[64];
    #pragma unroll
    for (int k = 0; k < 64; ++k) wcol[k] = W[k * 64 + lane];
    for (int n = wid; n < NN; n += nwaves) {
        float xv = X[(size_t)n * 64 + lane];
        float acc = 0.f;
        #pragma unroll
        for (int k = 0; k < 64; ++k) acc = fmaf(rlf(xv, k), wcol[k], acc);
        Hout[(size_t)n * 64 + lane] = disq[n] * acc;
    }
}

// ---------------- CSR conv: out = act(disq*(sum_neigh H + H_self) + b) [+res]
// one wave per node, lane = channel; indices fetched cooperatively, 4-deep gathers
__global__ __launch_bounds__(256) void k_csr_conv(
    const float* __restrict__ H, const int* __restrict__ rowptr,
    const int* __restrict__ esrc, const float* __restrict__ disq,
    const float* __restrict__ b, const float* __restrict__ res,
    float* __restrict__ out, int do_lrelu) {
    int lane = threadIdx.x & 63;
    int n = (blockIdx.x * 256 + threadIdx.x) >> 6;
    if (n >= NN) return;
    int beg = rowptr[n], end = rowptr[n + 1];
    float acc = H[(size_t)n * 64 + lane];  // self-loop
    for (int base = beg; base < end; base += 64) {
        int cnt = min(64, end - base);
        int idx = (lane < cnt) ? esrc[base + lane] : 0;
        int j = 0;
        for (; j + 4 <= cnt; j += 4) {
            int s0 = __builtin_amdgcn_readlane(idx, j);
            int s1 = __builtin_amdgcn_readlane(idx, j + 1);
            int s2 = __builtin_amdgcn_readlane(idx, j + 2);
            int s3 = __builtin_amdgcn_readlane(idx, j + 3);
            float h0 = H[(size_t)s0 * 64 + lane];
            float h1 = H[(size_t)s1 * 64 + lane];
            float h2 = H[(size_t)s2 * 64 + lane];
            float h3 = H[(size_t)s3 * 64 + lane];
            acc += (h0 + h1) + (h2 + h3);
        }
        for (; j < cnt; ++j) {
            int s = __builtin_amdgcn_readlane(idx, j);
            acc += H[(size_t)s * 64 + lane];
        }
    }
    float v = disq[n] * acc + b[lane];
    if (do_lrelu) v = (v >= 0.0f) ? v : 0.2f * v;
    if (res) v += res[(size_t)n * 64 + lane];
    out[(size_t)n * 64 + lane] = v;
}

// ---------------- CSR conv fused with final 64->2 projection (conv4) ----
__global__ __launch_bounds__(256) void k_csr_conv_final(
    const float* __restrict__ H, const int* __restrict__ rowptr,
    const int* __restrict__ esrc, const float* __restrict__ disq,
    const float* __restrict__ b, const float* __restrict__ res,
    const float* __restrict__ FW, const float* __restrict__ fb,
    float* __restrict__ out) {
    int lane = threadIdx.x & 63;
    int n = (blockIdx.x * 256 + threadIdx.x) >> 6;
    if (n >= NN) return;
    int beg = rowptr[n], end = rowptr[n + 1];
    float acc = H[(size_t)n * 64 + lane];
    for (int base = beg; base < end; base += 64) {
        int cnt = min(64, end - base);
        int idx = (lane < cnt) ? esrc[base + lane] : 0;
        int j = 0;
        for (; j + 4 <= cnt; j += 4) {
            int s0 = __builtin_amdgcn_readlane(idx, j);
            int s1 = __builtin_amdgcn_readlane(idx, j + 1);
            int s2 = __builtin_amdgcn_readlane(idx, j + 2);
            int s3 = __builtin_amdgcn_readlane(idx, j + 3);
            float h0 = H[(size_t)s0 * 64 + lane];
            float h1 = H[(size_t)s1 * 64 + lane];
            float h2 = H[(size_t)s2 * 64 + lane];
            float h3 = H[(size_t)s3 * 64 + lane];
            acc += (h0 + h1) + (h2 + h3);
        }
        for (; j < cnt; ++j) {
            int s = __builtin_amdgcn_readlane(idx, j);
            acc += H[(size_t)s * 64 + lane];
        }
    }
    float v = disq[n] * acc + b[lane] + res[(size_t)n * 64 + lane];  // out4
    float p0 = v * FW[lane * 2 + 0];
    float p1 = v * FW[lane * 2 + 1];
    for (int off = 32; off; off >>= 1) {
        p0 += __shfl_xor(p0, off, 64);
        p1 += __shfl_xor(p1, off, 64);
    }
    if (lane == 0) {
        out[n * 2 + 0] = p0 + fb[0];
        out[n * 2 + 1] = p1 + fb[1];
    }
}

extern "C" void kernel_launch(void* const* d_in, const int* in_sizes, int n_in,
                              void* d_out, int out_size, void* d_ws, size_t ws_size,
                              hipStream_t stream) {
    const float* nf   = (const float*)d_in[0];
    const int*   ei   = (const int*)d_in[1];
    const float* fc1W = (const float*)d_in[2];
    const float* fc1b = (const float*)d_in[3];
    const float* fc2W = (const float*)d_in[4];
    const float* fc2b = (const float*)d_in[5];
    const float* cW[4] = {(const float*)d_in[6], (const float*)d_in[8],
                          (const float*)d_in[10], (const float*)d_in[12]};
    const float* cb[4] = {(const float*)d_in[7], (const float*)d_in[9],
                          (const float*)d_in[11], (const float*)d_in[13]};
    const float* fW = (const float*)d_in[14];
    const float* fb = (const float*)d_in[15];
    const int* src = ei;
    const int* dst = ei + NE;

    float* ws     = (float*)d_ws;
    float* disq   = ws;                          // 50048 f
    int*   cnt    = (int*)(ws + 50048);          // 50048 i (histogram, then cursor)
    int*   rowptr = cnt + 50048;                 // 50056 i
    int*   esrc   = rowptr + 50056;              // 800000 i
    float* B0     = (float*)(esrc + 800000);     // NN*64 f
    float* B1     = B0 + (size_t)NN * 64;        // NN*64 f
    float* Hh     = B1 + (size_t)NN * 64;        // NN*64 f

    // ---- CSR build (once, shared by all 4 convs) ----
    hipMemsetAsync(cnt, 0, 50048 * sizeof(int), stream);
    k_hist<<<(NE + 255) / 256, 256, 0, stream>>>(dst, cnt);
    k_disq<<<(NN + 255) / 256, 256, 0, stream>>>(cnt, disq);
    k_scan<<<1, 1024, 0, stream>>>(cnt, rowptr);
    hipMemsetAsync(cnt, 0, 50048 * sizeof(int), stream);
    k_fill<<<(NE + 255) / 256, 256, 0, stream>>>(src, dst, rowptr, cnt, esrc);

    // ---- fc stack -> B0 ----
    k_fc<<<1024, 256, 0, stream>>>(nf, fc1W, fc1b, fc2W, fc2b, B0);

    const int cgrid = (NN * 64 + 255) / 256;  // one wave per node

    // conv1: out1 -> B1
    k_gemm64<<<512, 256, 0, stream>>>(B0, cW[0], disq, Hh);
    k_csr_conv<<<cgrid, 256, 0, stream>>>(Hh, rowptr, esrc, disq, cb[0], nullptr, B1, 1);
    // conv2: out2 = lrelu(conv)+out1 -> B0
    k_gemm64<<<512, 256, 0, stream>>>(B1, cW[1], disq, Hh);
    k_csr_conv<<<cgrid, 256, 0, stream>>>(Hh, rowptr, esrc, disq, cb[1], B1, B0, 1);
    // conv3: out3 -> B1
    k_gemm64<<<512, 256, 0, stream>>>(B0, cW[2], disq, Hh);
    k_csr_conv<<<cgrid, 256, 0, stream>>>(Hh, rowptr, esrc, disq, cb[2], nullptr, B1, 1);
    // conv4 + final projection -> d_out
    k_gemm64<<<512, 256, 0, stream>>>(B1, cW[3], disq, Hh);
    k_csr_conv_final<<<cgrid, 256, 0, stream>>>(Hh, rowptr, esrc, disq, cb[3], B0,
                                                fW, fb, (float*)d_out);
}